// Round 1
// baseline (568.516 us; speedup 1.0000x reference)
//
#include <hip/hip_runtime.h>
#include <cstdint>
#include <cstddef>

typedef _Float16 h16;
typedef __attribute__((ext_vector_type(8))) _Float16 h16x8;
typedef __attribute__((ext_vector_type(4))) _Float16 h16x4;
typedef __attribute__((ext_vector_type(4))) float f32x4;

constexpr int B_ = 64, LD = 512, LQ = 128, DIM = 512, STEPS = 2;
constexpr int MD = B_ * LD;   // 32768 d-rows total
constexpr int MQ = B_ * LQ;   // 8192 q-rows total
constexpr int KST = LD + LQ;  // 640 stacked-neighbor K
constexpr int KAGG = KST + DIM;  // 1152 = mask|node augmented K for agg GEMM

// async global->LDS, 16B per lane; LDS dest must be wave-uniform base + lane*16
#define ASYNC16(gp, lp)                                                          \
  __builtin_amdgcn_global_load_lds(                                              \
      (const __attribute__((address_space(1))) unsigned int*)(gp),               \
      (__attribute__((address_space(3))) unsigned int*)(lp), 16, 0, 0)

// A GEMM operand that switches source at k = ksplit (both K-contiguous).
struct Src {
  const h16* p0; int s0; long bstr0;  // rows for k in [0, ksplit)
  const h16* p1; int s1; long bstr1;  // rows for k in [ksplit, K)
  int ksplit;
};

// ---------------------------------------------------------------------------
// C = A * B^T tile kernel body. Block tile (WM*32) x 128, 4 waves as 2x2,
// each wave (WM*16) x 64 via WMx4 mfma_f32_16x16x32_f16 (fp32 accum).
// Pipeline (this revision): 3 LDS buffers, prefetch depth 2, counted
// s_waitcnt vmcnt(L) + raw s_barrier per K-step (T4). The wait leaves the
// younger in-flight tile's DMA outstanding (L = loads/tile/wave: 6 for WM=8,
// 4 for WM=4) instead of __syncthreads' vmcnt(0) full drain; the consumed
// tile's DMA was issued two mfmaSteps (~1300cy) earlier -> HBM latency
// covered. WAR: dma(t+2) targets the buffer last read at t-1 and is issued
// only after barrier(t), by which time every wave consumed its fragments.
// LDS swizzle (DMA-compatible, lane-linear dest): 16B chunk (row,kq) at
// chunk index row*4 + (kq ^ e(row)), e(row)=(row^(row>>2))&3. Staging thread
// t writes chunk t + 256*s; fragment ds_read_b128 covers all 8 bank-quads
// per 8-lane phase (conflict-free).
// MFMA 16x16x32 layouts (measured, m89/m91):
//   A-frag: m = lane&15, k = quad*8 + j ; B-frag: n = lane&15, k = quad*8+j
//   C/D:    col(n) = lane&15, row(m) = quad*4 + r
// ---------------------------------------------------------------------------
template <int WM, class Epi>
__device__ __forceinline__ void gemm_body(int b, long tileM, long tileN,
                                          Src sa, Src sb, int K,
                                          const Epi& epi, h16* lds) {
  constexpr int BM = WM * 32;        // block M: 256 or 128
  constexpr int AS = BM / 64;        // A staging segments: 4 or 2
  constexpr int AE = BM * 32;        // A elems per buffer
  constexpr int BUFE = AE + 4096;    // buffer stride in h16 elems

  const int tid = threadIdx.x;
  const int lane = tid & 63;
  const int wv = tid >> 6;
  const int wi = wv >> 1, wj = wv & 1;
  const int quad = lane >> 4, l16 = lane & 15;

  // staging mapping: thread t -> LDS chunk t (+256*s); global (row, kq)
  const int r = tid >> 2;                       // 0..63
  const int es = (r ^ (r >> 2)) & 3;
  const int kq = (tid & 3) ^ es;                // permuted k-quarter

  const h16* pa[2][AS];
  const h16* pb[2][2];
#pragma unroll
  for (int s = 0; s < AS; s++) {
    pa[0][s] = sa.p0 + (size_t)b * sa.bstr0 + (tileM + r + 64 * s) * (long)sa.s0 + kq * 8;
    pa[1][s] = sa.p1 + (size_t)b * sa.bstr1 + (tileM + r + 64 * s) * (long)sa.s1 + kq * 8 - sa.ksplit;
  }
#pragma unroll
  for (int s = 0; s < 2; s++) {
    pb[0][s] = sb.p0 + (size_t)b * sb.bstr0 + (tileN + r + 64 * s) * (long)sb.s0 + kq * 8;
    pb[1][s] = sb.p1 + (size_t)b * sb.bstr1 + (tileN + r + 64 * s) * (long)sb.s1 + kq * 8 - sb.ksplit;
  }

  // fragment LDS element offsets (buf 0); e depends only on l16
  const int ef = (l16 ^ (l16 >> 2)) & 3;
  int offA[WM], offB[4];
#pragma unroll
  for (int i = 0; i < WM; i++) {
    const int row = wi * WM * 16 + i * 16 + l16;
    offA[i] = (row * 4 + (quad ^ ef)) * 8;
  }
#pragma unroll
  for (int j = 0; j < 4; j++) {
    const int row = wj * 64 + j * 16 + l16;
    offB[j] = AE + (row * 4 + (quad ^ ef)) * 8;
  }

  f32x4 acc[WM][4] = {};
  const int T = K >> 5;

  auto dmaTile = [&](int t, int off) {
    const int k0 = t * 32;
    h16* base = lds + off + tid * 8;
    const int sel = (k0 >= sa.ksplit);
#pragma unroll
    for (int s = 0; s < AS; s++) ASYNC16(pa[sel][s] + k0, base + s * 2048);
    const int selb = (k0 >= sb.ksplit);
#pragma unroll
    for (int s = 0; s < 2; s++) ASYNC16(pb[selb][s] + k0, base + AE + s * 2048);
  };
  auto mfmaStep = [&](int off) {
    h16x8 af[WM], bf[4];
#pragma unroll
    for (int i = 0; i < WM; i++) af[i] = *(const h16x8*)(lds + off + offA[i]);
#pragma unroll
    for (int j = 0; j < 4; j++) bf[j] = *(const h16x8*)(lds + off + offB[j]);
#pragma unroll
    for (int i = 0; i < WM; i++)
#pragma unroll
      for (int j = 0; j < 4; j++)
        acc[i][j] = __builtin_amdgcn_mfma_f32_16x16x32_f16(af[i], bf[j], acc[i][j], 0, 0, 0);
  };

  // prologue: 2 tiles in flight
  dmaTile(0, 0);
  dmaTile(1, BUFE);

  int co = 0;            // buffer offset to consume (tile t)
  int no = 2 * BUFE;     // buffer offset for issue (tile t+2)
  for (int t = 0; t < T - 1; ++t) {
    // own dma(t) done; dma(t+1) stays in flight (counted wait, no drain)
    if constexpr (WM == 8) asm volatile("s_waitcnt vmcnt(6)" ::: "memory");
    else                   asm volatile("s_waitcnt vmcnt(4)" ::: "memory");
    __builtin_amdgcn_s_barrier();            // all waves' dma(t) done; WAR gate
    asm volatile("" ::: "memory");
    __builtin_amdgcn_sched_barrier(0);
    if (t + 2 < T) dmaTile(t + 2, no);
    mfmaStep(co);
    co = (co == 2 * BUFE) ? 0 : co + BUFE;
    no = (no == 2 * BUFE) ? 0 : no + BUFE;
  }
  // last K-step: nothing younger in flight -> full drain
  asm volatile("s_waitcnt vmcnt(0)" ::: "memory");
  __builtin_amdgcn_s_barrier();
  asm volatile("" ::: "memory");
  __builtin_amdgcn_sched_barrier(0);
  mfmaStep(co);

#pragma unroll
  for (int i = 0; i < WM; i++) {
#pragma unroll
    for (int j = 0; j < 4; j++) {
      const int gm0 = (int)tileM + wi * WM * 16 + i * 16 + quad * 4;
      const int gn  = (int)tileN + wj * 64 + j * 16 + l16;
#pragma unroll
      for (int rr = 0; rr < 4; rr++) epi(b, gm0 + rr, gn, acc[i][j][rr]);
    }
  }
}

// --- epilogues --------------------------------------------------------------
// Dense GEMM: A = [W_x|W_y] (1024 rows), Bt = node (all batches), C[o][node].
struct EpiDense {
  const float* w;   // gate per node (indexed by gn)
  h16* stackA;      // gm <  512 -> stackA[b][gm][offA + l]
  h16* stackB;      // gm >= 512 -> stackB[b][gm-512][offB + l]
  int lnShift;      // nodes-per-batch shift: 9 (d) or 7 (q)
  int offA, offB;
  __device__ void operator()(int, int gm, int gn, float v) const {
    const int b = gn >> lnShift, l = gn & ((1 << lnShift) - 1);
    const h16 sv = (h16)(w[gn] * v);
    if (gm < 512)
      stackA[((size_t)b * 512 + gm) * 640 + offA + l] = sv;
    else
      stackB[((size_t)b * 512 + (gm - 512)) * 640 + offB + l] = sv;
  }
};
// Agg GEMM: A = [mask'|node], Bt = [stackT|W_self], C[i][c] = self + msg/nb.
// nodeNext == nullptr on the last iteration (result never re-read).
struct EpiAgg {
  const float* bias;  // b_self[c]
  float* out;         // fp32 final output or nullptr
  h16* nodeNext;      // next-iteration node buffer [i][c], or nullptr
  int rowsPerB;       // 512 (d) or 128 (q)
  __device__ void operator()(int b, int gm, int gn, float v) const {
    const size_t row = (size_t)b * rowsPerB + gm;
    const float val = fmaxf(v + bias[gn], 0.f);
    if (out) out[row * 512 + gn] = val;
    if (nodeNext) nodeNext[row * 512 + gn] = (h16)val;
  }
};

// ---------------------------------------------------------------------------
// Combined dense launch: 1280 blocks. g = x*320 + yy; x = M-tile of 256
// (0..3), yy<256 -> d-job (tileN=yy*128), else q-job (yy-256). Same-yy blocks
// are 320 apart => same XCD (L2 reuse of the shared node B-tile).
// ---------------------------------------------------------------------------
__global__ __launch_bounds__(256, 2) void k_dense(Src saD, Src sbD, EpiDense epiD,
                                                  Src saQ, Src sbQ, EpiDense epiQ) {
  __shared__ __align__(16) h16 lds[3 * (256 * 32 + 128 * 32)];  // 72 KB, 3 bufs
  const int g = blockIdx.x;
  const int x = g / 320;
  const int yy = g % 320;
  if (yy < 256)
    gemm_body<8>(0, (long)x * 256, (long)yy * 128, saD, sbD, 512, epiD, lds);
  else
    gemm_body<8>(0, (long)x * 256, (long)(yy - 256) * 128, saQ, sbQ, 512, epiQ, lds);
}

// Combined agg launch: 768 blocks. g = inner*64 + b. q-jobs dispatch FIRST
// (inner<4 -> q, y=inner; inner>=4 -> d, i2=inner-4: x=i2>>2, y=i2&3) so the
// half-cost q-blocks pair with d-blocks instead of forming a 1-block/CU tail.
// Same-batch blocks are 64 apart => same XCD (per-batch working set ~3MB).
__global__ __launch_bounds__(256, 2) void k_agg(Src saD, Src sbD, EpiAgg epiD,
                                                Src saQ, Src sbQ, EpiAgg epiQ) {
  __shared__ __align__(16) h16 lds[3 * (256 * 32 + 128 * 32)];  // 72 KB, 3 bufs
  const int g = blockIdx.x;
  const int b = g & 63;
  const int inner = g >> 6;
  if (inner >= 4) {
    const int i2 = inner - 4;
    gemm_body<8>(b, (long)(i2 >> 2) * 256, (long)(i2 & 3) * 128, saD, sbD, KAGG, epiD, lds);
  } else {
    gemm_body<4>(b, 0L, (long)inner * 128, saQ, sbQ, KAGG, epiQ, lds);
  }
}

// --- small kernels ----------------------------------------------------------
__global__ __launch_bounds__(256) void k_convert(const float* __restrict__ dn,
                                                 const float* __restrict__ qn,
                                                 h16* __restrict__ dnb,
                                                 h16* __restrict__ qnb) {
  const size_t i4 = ((size_t)blockIdx.x * 256 + threadIdx.x) * 4;
  constexpr size_t TD = (size_t)MD * DIM;
  const float* src; h16* dst; size_t idx;
  if (i4 < TD) { src = dn; dst = dnb; idx = i4; }
  else         { src = qn; dst = qnb; idx = i4 - TD; }
  const float4 v = *(const float4*)&src[idx];
  h16x4 o; o.x = (h16)v.x; o.y = (h16)v.y; o.z = (h16)v.z; o.w = (h16)v.w;
  *(h16x4*)&dst[idx] = o;
}

__global__ __launch_bounds__(256) void k_wcat(const float* __restrict__ Wself,
                                              const float* __restrict__ Wdd,
                                              const float* __restrict__ Wqd,
                                              const float* __restrict__ Wqq,
                                              const float* __restrict__ Wdq,
                                              h16* __restrict__ catD,
                                              h16* __restrict__ catQ) {
  const int i = blockIdx.x * 256 + threadIdx.x;  // < 1536*512
  float vD, vQ;
  if (i < 512 * 512)       { vD = Wself[i];            vQ = vD; }
  else if (i < 1024 * 512) { vD = Wdd[i - 512 * 512];  vQ = Wqq[i - 512 * 512]; }
  else                     { vD = Wqd[i - 1024 * 512]; vQ = Wdq[i - 1024 * 512]; }
  catD[i] = (h16)vD; catQ[i] = (h16)vQ;
}

// maskD'[b][i][j] = graph/nb : j<512 dd, else dq (premultiplied by 1/max(nb,1))
__global__ __launch_bounds__(256) void k_maskD(const int* __restrict__ dd,
                                               const int* __restrict__ dq,
                                               h16* __restrict__ maskD) {
  const int row = blockIdx.x * 4 + (threadIdx.x >> 6);
  const int lane = threadIdx.x & 63;
  const int* pdd = dd + (size_t)row * 512;
  const int* pdq = dq + (size_t)row * 128;
  h16* pm = maskD + (size_t)row * 640;
  float vals[10];
  float s = 0.f;
#pragma unroll
  for (int t = 0; t < 10; t++) {
    const int j = lane + t * 64;
    const float v = (float)((j < 512) ? pdd[j] : pdq[j - 512]);
    vals[t] = v; s += v;
  }
  for (int m = 32; m; m >>= 1) s += __shfl_xor(s, m);
  const float inv = 1.f / fmaxf(s, 1.f);
#pragma unroll
  for (int t = 0; t < 10; t++) pm[lane + t * 64] = (h16)(vals[t] * inv);
}

__global__ __launch_bounds__(256) void k_maskQ(const int* __restrict__ qq,
                                               const int* __restrict__ qd,
                                               h16* __restrict__ maskQ) {
  const int row = blockIdx.x * 4 + (threadIdx.x >> 6);
  const int lane = threadIdx.x & 63;
  const int* pqq = qq + (size_t)row * 128;
  const int* pqd = qd + (size_t)row * 512;
  h16* pm = maskQ + (size_t)row * 640;
  float vals[10];
  float s = 0.f;
#pragma unroll
  for (int t = 0; t < 10; t++) {
    const int j = lane + t * 64;
    const float v = (float)((j < 128) ? pqq[j] : pqd[j - 128]);
    vals[t] = v; s += v;
  }
  for (int m = 32; m; m >>= 1) s += __shfl_xor(s, m);
  const float inv = 1.f / fmaxf(s, 1.f);
#pragma unroll
  for (int t = 0; t < 10; t++) pm[lane + t * 64] = (h16)(vals[t] * inv);
}

// sigmoid gate per node row: one wave per row (d rows then q rows)
__global__ __launch_bounds__(256) void k_w(const h16* __restrict__ dnb,
                                           const h16* __restrict__ qnb,
                                           const float* __restrict__ Wnw,
                                           const float* __restrict__ bnw,
                                           float* __restrict__ d_w,
                                           float* __restrict__ q_w,
                                           float* __restrict__ adw,
                                           float* __restrict__ aqw, int it) {
  const int row = blockIdx.x * 4 + (threadIdx.x >> 6);
  const int lane = threadIdx.x & 63;
  const bool isD = row < MD;
  const h16* node = isD ? dnb + (size_t)row * 512 : qnb + (size_t)(row - MD) * 512;
  const h16x8 v = *(const h16x8*)&node[lane * 8];
  const float4 w0 = *(const float4*)&Wnw[lane * 8];
  const float4 w1 = *(const float4*)&Wnw[lane * 8 + 4];
  float s = (float)v[0] * w0.x + (float)v[1] * w0.y + (float)v[2] * w0.z +
            (float)v[3] * w0.w + (float)v[4] * w1.x + (float)v[5] * w1.y +
            (float)v[6] * w1.z + (float)v[7] * w1.w;
  for (int m = 32; m; m >>= 1) s += __shfl_xor(s, m);
  if (lane == 0) {
    const float w = 1.f / (1.f + expf(-(s + bnw[0])));
    if (isD) {
      d_w[row] = w;
      adw[((size_t)(row >> 9) * STEPS + it) * 512 + (row & 511)] = w;
    } else {
      const int rq = row - MD;
      q_w[rq] = w;
      aqw[((size_t)(rq >> 7) * STEPS + it) * 128 + (rq & 127)] = w;
    }
  }
}

// ---------------------------------------------------------------------------
extern "C" void kernel_launch(void* const* d_in, const int* in_sizes, int n_in,
                              void* d_out, int out_size, void* d_ws, size_t ws_size,
                              hipStream_t stream) {
  (void)in_sizes; (void)n_in; (void)out_size; (void)ws_size;

  const float* d_node = (const float*)d_in[0];
  const float* q_node = (const float*)d_in[1];
  const int*   qq     = (const int*)d_in[2];
  const int*   dq     = (const int*)d_in[3];
  const int*   dd     = (const int*)d_in[4];
  const int*   qd     = (const int*)d_in[5];
  const float* W_nw   = (const float*)d_in[6];
  const float* b_nw   = (const float*)d_in[7];
  const float* W_self = (const float*)d_in[8];
  const float* b_self = (const float*)d_in[9];
  const float* W_dd   = (const float*)d_in[10];
  const float* W_qq   = (const float*)d_in[11];
  const float* W_dq   = (const float*)d_in[12];
  const float* W_qd   = (const float*)d_in[13];

  float* outd = (float*)d_out;                  // [B,Ld,D]
  float* outq = outd + (size_t)MD * DIM;        // [B,Lq,D]
  float* adw  = outq + (size_t)MQ * DIM;        // [B,STEPS,Ld]
  float* aqw  = adw + (size_t)B_ * STEPS * LD;  // [B,STEPS,Lq]

  char* p = (char*)d_ws;
  auto alloc = [&](size_t bytes) { char* r = p; p += (bytes + 255) & ~(size_t)255; return r; };
  h16* dnode[2], *qnode[2];
  dnode[0] = (h16*)alloc((size_t)MD * DIM * 2);
  dnode[1] = (h16*)alloc((size_t)MD * DIM * 2);
  qnode[0] = (h16*)alloc((size_t)MQ * DIM * 2);
  qnode[1] = (h16*)alloc((size_t)MQ * DIM * 2);
  h16* catD    = (h16*)alloc((size_t)1536 * 512 * 2);
  h16* catQ    = (h16*)alloc((size_t)1536 * 512 * 2);
  h16* maskD   = (h16*)alloc((size_t)B_ * LD * KST * 2);
  h16* maskQ   = (h16*)alloc((size_t)B_ * LQ * KST * 2);
  h16* stackDT = (h16*)alloc((size_t)B_ * 512 * KST * 2);
  h16* stackQT = (h16*)alloc((size_t)B_ * 512 * KST * 2);
  float* d_wb  = (float*)alloc((size_t)MD * 4);
  float* q_wb  = (float*)alloc((size_t)MQ * 4);

  // one-time prep
  k_convert<<<dim3((MD * DIM + MQ * DIM) / 4 / 256), 256, 0, stream>>>(d_node, q_node, dnode[0], qnode[0]);
  k_wcat<<<dim3(1536 * 512 / 256), 256, 0, stream>>>(W_self, W_dd, W_qd, W_qq, W_dq, catD, catQ);
  k_maskD<<<dim3(MD / 4), 256, 0, stream>>>(dd, dq, maskD);
  k_maskQ<<<dim3(MQ / 4), 256, 0, stream>>>(qq, qd, maskQ);

  for (int it = 0; it < STEPS; it++) {
    const bool last = (it == STEPS - 1);
    h16* ncur_d = dnode[it & 1];
    h16* nnext_d = dnode[(it & 1) ^ 1];
    h16* ncur_q = qnode[it & 1];
    h16* nnext_q = qnode[(it & 1) ^ 1];

    k_w<<<dim3((MD + MQ) / 4), 256, 0, stream>>>(ncur_d, ncur_q, W_nw, b_nw, d_wb, q_wb, adw, aqw, it);

    // combined dense: d-job A=catD[512:1536]=[W_dd|W_qd] Bt=dnode;
    //                 q-job A=catQ[512:1536]=[W_qq|W_dq] Bt=qnode
    {
      Src saD{catD + 512 * 512, 512, 0, catD + 512 * 512, 512, 0, 512};
      Src sbD{ncur_d, 512, 0, ncur_d, 512, 0, 512};
      Src saQ{catQ + 512 * 512, 512, 0, catQ + 512 * 512, 512, 0, 512};
      Src sbQ{ncur_q, 512, 0, ncur_q, 512, 0, 512};
      k_dense<<<dim3(1280), 256, 0, stream>>>(
          saD, sbD, EpiDense{d_wb, stackDT, stackQT, 9, 0, 128},
          saQ, sbQ, EpiDense{q_wb, stackQT, stackDT, 7, 0, 512});
    }
    // combined agg: d-job A=[maskD'|dnode] Bt=[stackDT|W_self];
    //               q-job A=[maskQ'|qnode] Bt=[stackQT|W_self]
    {
      Src saD{maskD, 640, (long)LD * KST, ncur_d, 512, (long)LD * DIM, KST};
      Src sbD{stackDT, 640, (long)512 * KST, catD, 512, 0, KST};
      Src saQ{maskQ, 640, (long)LQ * KST, ncur_q, 512, (long)LQ * DIM, KST};
      Src sbQ{stackQT, 640, (long)512 * KST, catQ, 512, 0, KST};
      k_agg<<<dim3(768), 256, 0, stream>>>(
          saD, sbD, EpiAgg{b_self, last ? outd : nullptr, last ? nullptr : nnext_d, 512},
          saQ, sbQ, EpiAgg{b_self, last ? outq : nullptr, last ? nullptr : nnext_q, 128});
    }
  }
}